// Round 8
// baseline (880.413 us; speedup 1.0000x reference)
//
#include <hip/hip_runtime.h>

typedef unsigned int uint32;
typedef unsigned int v4u __attribute__((ext_vector_type(4)));

__device__ __forceinline__ uint32 nib_of(v4u b) {
    // pulse word is exactly 0x3F800000 (1.0f) or 0x00000000; test bit 29.
    return ((b.x >> 26) & 8u) | ((b.y >> 27) & 4u) |
           ((b.z >> 28) & 2u) | ((b.w >> 29) & 1u);
}

__device__ __forceinline__ uint32 butterfly_or(uint32 u) {
    // OR across the aligned 8-lane group: every lane gets the full 32-bit word
    u |= __shfl_xor(u, 1);
    u |= __shfl_xor(u, 2);
    u |= __shfl_xor(u, 4);
    return u;
}

__device__ __forceinline__ uint32 tanh_bits(uint32 u) {
    // exact FP64 op sequence of the reference
    double v = (double)__uint_as_float(u);
    double e2x = exp(2.0 * v);
    double t64 = (e2x - 1.0) / (e2x + 1.0);
    return __float_as_uint((float)t64);
}

__device__ __forceinline__ v4u expand_nibble(uint32 ru, int shift) {
    uint32 onib = (ru >> shift) & 0xFu;
    v4u o;
    o.x = (onib & 8u) ? 0x3F800000u : 0u;
    o.y = (onib & 4u) ? 0x3F800000u : 0u;
    o.z = (onib & 2u) ? 0x3F800000u : 0u;
    o.w = (onib & 1u) ? 0x3F800000u : 0u;
    return o;
}

__global__ __launch_bounds__(256) void
spike_tanh_kernel(const v4u* __restrict__ in, v4u* __restrict__ out,
                  int n_vec4, int n_main) {
    const int stride  = gridDim.x * blockDim.x;       // v4u elements per sweep
    const int lane    = threadIdx.x & 63;
    const int p       = lane & 7;                     // position within 8-group
    const int shift   = 4 * (7 - p);                  // MSB-first nibble of this lane
    const int srcbase = lane & ~7;                    // group base for result gather
    int i = blockIdx.x * blockDim.x + threadIdx.x;

    // main loop: 8 grid-strided chunks per superiteration.
    // Each chunk's butterfly gives 8 scalars (one per 8-lane group); lane l
    // keeps chunk k=l&7's word -> 64 distinct scalars per wave -> ONE tanh
    // wave-execution per 64 scalars instead of 8.
    for (; i < n_main; i += 8 * stride) {
        v4u a0 = __builtin_nontemporal_load(in + i);
        v4u a1 = __builtin_nontemporal_load(in + i + stride);
        v4u a2 = __builtin_nontemporal_load(in + i + 2 * stride);
        v4u a3 = __builtin_nontemporal_load(in + i + 3 * stride);
        v4u a4 = __builtin_nontemporal_load(in + i + 4 * stride);
        v4u a5 = __builtin_nontemporal_load(in + i + 5 * stride);
        v4u a6 = __builtin_nontemporal_load(in + i + 6 * stride);
        v4u a7 = __builtin_nontemporal_load(in + i + 7 * stride);

        uint32 u0 = butterfly_or(nib_of(a0) << shift);
        uint32 u1 = butterfly_or(nib_of(a1) << shift);
        uint32 u2 = butterfly_or(nib_of(a2) << shift);
        uint32 u3 = butterfly_or(nib_of(a3) << shift);
        uint32 u4 = butterfly_or(nib_of(a4) << shift);
        uint32 u5 = butterfly_or(nib_of(a5) << shift);
        uint32 u6 = butterfly_or(nib_of(a6) << shift);
        uint32 u7 = butterfly_or(nib_of(a7) << shift);

        // lane l owns chunk k = l&7 (7-step select; conditions are loop-invariant)
        uint32 U = u0;
        U = (p == 1) ? u1 : U;
        U = (p == 2) ? u2 : U;
        U = (p == 3) ? u3 : U;
        U = (p == 4) ? u4 : U;
        U = (p == 5) ? u5 : U;
        U = (p == 6) ? u6 : U;
        U = (p == 7) ? u7 : U;

        uint32 R = tanh_bits(U);   // one FP64 tanh for 64 distinct scalars

        // chunk k's scalar for group g=l>>3 is owned by lane (l&~7)+k;
        // broadcast it to the group, each lane emits its own nibble.
#pragma unroll
        for (int k = 0; k < 8; ++k) {
            uint32 rk = __shfl(R, srcbase + k);
            __builtin_nontemporal_store(expand_nibble(rk, shift),
                                        out + i + k * stride);
        }
    }
    // generic tail (empty for N=4M scalars with grid 2048x256): R3-style
    // redundant-compute path; whole 8-lane groups exit together.
    for (; i < n_vec4; i += stride) {
        v4u a = __builtin_nontemporal_load(in + i);
        uint32 r = tanh_bits(butterfly_or(nib_of(a) << shift));
        __builtin_nontemporal_store(expand_nibble(r, shift), out + i);
    }
}

extern "C" void kernel_launch(void* const* d_in, const int* in_sizes, int n_in,
                              void* d_out, int out_size, void* d_ws, size_t ws_size,
                              hipStream_t stream) {
    (void)n_in; (void)d_ws; (void)ws_size; (void)out_size;
    const int n_vec4 = in_sizes[0] / 4;             // 33,554,432 uint4s
    const v4u* in  = (const v4u*)d_in[0];
    v4u*       out = (v4u*)d_out;

    const int block = 256;
    long grid_l = ((long)n_vec4 + block - 1) / block;
    int grid = grid_l > 2048 ? 2048 : (int)grid_l;
    const int stride = grid * block;                // 524,288
    const int chunk  = 8 * stride;
    const int n_main = (n_vec4 / chunk) * chunk;    // == n_vec4 here (8 superiters)
    spike_tanh_kernel<<<grid, block, 0, stream>>>(in, out, n_vec4, n_main);
}

// Round 10
// 805.681 us; speedup vs baseline: 1.0928x; 1.0928x over previous
//
#include <hip/hip_runtime.h>

typedef unsigned int uint32;
typedef unsigned int v4u __attribute__((ext_vector_type(4)));

__device__ __forceinline__ uint32 nib_of(v4u b) {
    // pulse word is exactly 0x3F800000 (1.0f) or 0x00000000; test bit 29.
    return ((b.x >> 26) & 8u) | ((b.y >> 27) & 4u) |
           ((b.z >> 28) & 2u) | ((b.w >> 29) & 1u);
}

__device__ __forceinline__ uint32 butterfly_or(uint32 u) {
    // OR across the aligned 8-lane group: every lane gets the full 32-bit word
    u |= __shfl_xor(u, 1);
    u |= __shfl_xor(u, 2);
    u |= __shfl_xor(u, 4);
    return u;
}

__device__ __forceinline__ uint32 tanh_bits(uint32 u) {
    // exact FP64 op sequence of the reference
    double v = (double)__uint_as_float(u);
    double e2x = exp(2.0 * v);
    double t64 = (e2x - 1.0) / (e2x + 1.0);
    return __float_as_uint((float)t64);
}

__device__ __forceinline__ v4u expand_nibble(uint32 ru, int shift) {
    uint32 onib = (ru >> shift) & 0xFu;
    v4u o;
    o.x = (onib & 8u) ? 0x3F800000u : 0u;
    o.y = (onib & 4u) ? 0x3F800000u : 0u;
    o.z = (onib & 2u) ? 0x3F800000u : 0u;
    o.w = (onib & 1u) ? 0x3F800000u : 0u;
    return o;
}

// Flat kernel: one v4u per thread, no loop, minimal VGPRs, max resident waves.
// Latency hiding comes entirely from wave-level parallelism + fast wave turnover.
__global__ __launch_bounds__(256) void
spike_tanh_kernel(const v4u* __restrict__ in, v4u* __restrict__ out, int n_vec4) {
    const int i = blockIdx.x * blockDim.x + threadIdx.x;
    if (i >= n_vec4) return;                          // uniform; whole groups exit
    const int shift = 4 * (7 - (threadIdx.x & 7));    // MSB-first nibble of this lane

    v4u a = __builtin_nontemporal_load(in + i);
    uint32 u = butterfly_or(nib_of(a) << shift);
    uint32 r = tanh_bits(u);
    __builtin_nontemporal_store(expand_nibble(r, shift), out + i);
}

extern "C" void kernel_launch(void* const* d_in, const int* in_sizes, int n_in,
                              void* d_out, int out_size, void* d_ws, size_t ws_size,
                              hipStream_t stream) {
    (void)n_in; (void)d_ws; (void)ws_size; (void)out_size;
    const int n_vec4 = in_sizes[0] / 4;               // 33,554,432 uint4s
    const v4u* in  = (const v4u*)d_in[0];
    v4u*       out = (v4u*)d_out;

    const int block = 256;
    const int grid  = (n_vec4 + block - 1) / block;   // 131072 blocks, exact cover
    spike_tanh_kernel<<<grid, block, 0, stream>>>(in, out, n_vec4);
}